// Round 14
// baseline (613.702 us; speedup 1.0000x reference)
//
#include <hip/hip_runtime.h>
#include <math.h>

// ---------------------------------------------------------------------------
// MultiStreamCNN. R14:
//  - fuse: wave de-phasing. MfmaUtil 40% == 2-wave pipe ceiling with lockstep
//    stall phases (both SIMD-resident waves run identical streams started
//    together). Rotate each wave's chunk order by ((wsub+ypair)&3)*9 tc so
//    co-resident waves stall at different times. Dropped R13's neutral B
//    register prefetch. Chunk rotation only reorders the fp32 accumulation
//    (commutative sum; error << 0.195 threshold).
//  - conv2: stageB reads w2 COALESCED (float4 linear) + transpose-in-LDS
//    (was stride-36B scalar: 36 lines/wave-load, ~5.7k line txns/block).
//  - wprep absorbs zero_feat (one less launch).
// ---------------------------------------------------------------------------

typedef __bf16 bf16x8 __attribute__((ext_vector_type(8)));
typedef float f32x4 __attribute__((ext_vector_type(4)));

static __device__ __forceinline__ ushort f2bf(float f) {
    unsigned u = __float_as_uint(f);
    unsigned r = (u + 0x7fffu + ((u >> 16) & 1u)) >> 16;   // RNE
    return (ushort)r;
}
static __device__ __forceinline__ float bf2f(ushort h) {
    return __uint_as_float(((unsigned)h) << 16);
}

// ---------- Kernel A: conv3x3 (3->32) + bias + relu + maxpool2 --------------
__global__ __launch_bounds__(256) void conv1_pool(
    const float* __restrict__ x, const float* __restrict__ w,
    const float* __restrict__ bias, ushort* __restrict__ C1h,
    ushort* __restrict__ C1l)
{
    __shared__ float s[3 * 34 * 34];
    const int b = blockIdx.z;
    const int tileX = blockIdx.x, tileY = blockIdx.y;
    const int tid = threadIdx.x;
    const int tx = tid & 15, ty = tid >> 4;
    const int ih0 = tileY * 32 - 1, iw0 = tileX * 32 - 1;

    for (int i = tid; i < 3 * 34 * 34; i += 256) {
        int c = i / 1156, r = i % 1156;
        int y = r / 34, xx = r % 34;
        int ih = ih0 + y, iw = iw0 + xx;
        float v = 0.f;
        if (ih >= 0 && ih < 512 && iw >= 0 && iw < 512)
            v = x[((b * 3 + c) * 512 + ih) * 512 + iw];
        s[i] = v;
    }
    __syncthreads();

    float in[3][4][4];
#pragma unroll
    for (int c = 0; c < 3; ++c)
#pragma unroll
        for (int dy = 0; dy < 4; ++dy)
#pragma unroll
            for (int dx = 0; dx < 4; ++dx)
                in[c][dy][dx] = s[c * 1156 + (2 * ty + dy) * 34 + (2 * tx + dx)];

    const int oh = tileY * 16 + ty, ow = tileX * 16 + tx;
    __attribute__((aligned(16))) ushort hb[32];
    __attribute__((aligned(16))) ushort lb[32];
#pragma unroll
    for (int oc = 0; oc < 32; ++oc) {   // FULL unroll: hb/lb must stay in VGPRs
        const float bv = bias[oc];
        float m = -INFINITY;
#pragma unroll
        for (int py = 0; py < 2; ++py)
#pragma unroll
            for (int px = 0; px < 2; ++px) {
                float a = 0.f;
#pragma unroll
                for (int c = 0; c < 3; ++c)
#pragma unroll
                    for (int ky = 0; ky < 3; ++ky)
#pragma unroll
                        for (int kx = 0; kx < 3; ++kx)
                            a = fmaf(w[((oc * 3 + c) * 3 + ky) * 3 + kx],
                                     in[c][py + ky][px + kx], a);
                m = fmaxf(m, a);
            }
        m = fmaxf(m + bv, 0.f);
        ushort h = f2bf(m);
        hb[oc] = h;
        lb[oc] = f2bf(m - bf2f(h));
    }
    size_t base = ((size_t)((b * 256 + oh) * 256 + ow)) << 5;
    uint4* dh = (uint4*)(C1h + base);
    uint4* dl = (uint4*)(C1l + base);
#pragma unroll
    for (int k = 0; k < 4; ++k) {
        dh[k] = *(const uint4*)&hb[k * 8];
        dl[k] = *(const uint4*)&lb[k * 8];
    }
}

// ---------- Kernel B: conv2 as split-bf16 MFMA + maxpool2 -------------------
// Phased B staging (taps 0-4 then 5-8), COALESCED w2 reads + LDS transpose.
// Output CHUNK-PLANAR A[b][c(4)][y][x][32].
__global__ __launch_bounds__(256) void conv2_mfma(
    const ushort* __restrict__ C1h, const ushort* __restrict__ C1l,
    const float* __restrict__ w2, const float* __restrict__ bias,
    ushort* __restrict__ Ahi, ushort* __restrict__ Alo, int stream_base)
{
    __shared__ char lds[40960];            // union: B (40KB) then pool (32KB)
    ushort* Bh = (ushort*)lds;             // [rel_tap][oc*32+kk]
    ushort* Bl = (ushort*)(lds + 20480);
    float (*pool)[32][64] = (float (*)[32][64])lds;  // [4][32][64], after taps

    const int seg = blockIdx.x, Y = blockIdx.y, b = blockIdx.z;
    const int tid = threadIdx.x, wsub = tid >> 6, lane = tid & 63;
    const int n = lane & 15, q = lane >> 4;
    const int yc = 2 * Y + (wsub & 1);              // conv row in [0,256)
    const int wx0 = seg * 128 + (wsub >> 1) * 64;   // conv x base for wave

    const uint4 zero4 = make_uint4(0u, 0u, 0u, 0u);

    // coalesced read of all 18432 w2 floats; store only taps [t0, t0+ntap)
    auto stageB = [&](int t0, int ntap) {
        for (int base = tid * 4; base < 18432; base += 1024) {
            const float4 v4 = *(const float4*)(w2 + base);
#pragma unroll
            for (int j = 0; j < 4; ++j) {
                int idx = base + j;
                int t = idx % 9;
                int rel = t - t0;
                if ((unsigned)rel < (unsigned)ntap) {
                    int r = idx / 9;   // oc*32 + kk
                    float v = (j == 0) ? v4.x : (j == 1) ? v4.y : (j == 2) ? v4.z : v4.w;
                    ushort h = f2bf(v);
                    Bh[rel * 2048 + r] = h;
                    Bl[rel * 2048 + r] = f2bf(v - bf2f(h));
                }
            }
        }
    };

    auto loadA = [&](int t, uint4* aH, uint4* aL) {
        int ky = t / 3, kx = t - ky * 3;
        int yy = yc + ky - 1;
        bool yok = (yy >= 0) & (yy < 256);
#pragma unroll
        for (int mt = 0; mt < 4; ++mt) {
            int xp = wx0 + mt * 16 + n + kx - 1;
            bool ok = yok & (xp >= 0) & (xp < 256);
            int yyc = ok ? yy : 0, xpc = ok ? xp : 0;
            size_t off = (((size_t)((b * 256 + yyc) * 256 + xpc)) << 5) + q * 8;
            aH[mt] = ok ? *(const uint4*)(C1h + off) : zero4;
            aL[mt] = ok ? *(const uint4*)(C1l + off) : zero4;
        }
    };

    f32x4 acc[4][4];
#pragma unroll
    for (int mt = 0; mt < 4; ++mt)
#pragma unroll
        for (int nt = 0; nt < 4; ++nt) acc[mt][nt] = (f32x4){0.f, 0.f, 0.f, 0.f};

    uint4 aH[4], aL[4];
    loadA(0, aH, aL);
    stageB(0, 5);
    __syncthreads();   // phase-0 B staged

    for (int t = 0; t < 9; ++t) {
        if (t == 5) {               // phase switch: restage taps 5-8
            __syncthreads();        // all phase-0 B reads done
            stageB(5, 4);
            __syncthreads();
        }
        const int rel = (t < 5) ? t : t - 5;
        uint4 cH[4], cL[4];
#pragma unroll
        for (int mt = 0; mt < 4; ++mt) { cH[mt] = aH[mt]; cL[mt] = aL[mt]; }
        if (t + 1 < 9) loadA(t + 1, aH, aL);
        bf16x8 bh[4], bl[4];
#pragma unroll
        for (int nt = 0; nt < 4; ++nt) {
            int off = rel * 2048 + (nt * 16 + n) * 32 + q * 8;
            bh[nt] = __builtin_bit_cast(bf16x8, *(const uint4*)&Bh[off]);
            bl[nt] = __builtin_bit_cast(bf16x8, *(const uint4*)&Bl[off]);
        }
        // step-outer MFMA order (dep distance 16)
#pragma unroll
        for (int mt = 0; mt < 4; ++mt) {
            bf16x8 ah = __builtin_bit_cast(bf16x8, cH[mt]);
#pragma unroll
            for (int nt = 0; nt < 4; ++nt)
                acc[mt][nt] = __builtin_amdgcn_mfma_f32_16x16x32_bf16(ah, bh[nt], acc[mt][nt], 0, 0, 0);
        }
#pragma unroll
        for (int mt = 0; mt < 4; ++mt) {
            bf16x8 ah = __builtin_bit_cast(bf16x8, cH[mt]);
#pragma unroll
            for (int nt = 0; nt < 4; ++nt)
                acc[mt][nt] = __builtin_amdgcn_mfma_f32_16x16x32_bf16(ah, bl[nt], acc[mt][nt], 0, 0, 0);
        }
#pragma unroll
        for (int mt = 0; mt < 4; ++mt) {
            bf16x8 al = __builtin_bit_cast(bf16x8, cL[mt]);
#pragma unroll
            for (int nt = 0; nt < 4; ++nt)
                acc[mt][nt] = __builtin_amdgcn_mfma_f32_16x16x32_bf16(al, bh[nt], acc[mt][nt], 0, 0, 0);
        }
    }

    __syncthreads();   // all B reads done; safe to overwrite with pool

#pragma unroll
    for (int mt = 0; mt < 4; ++mt)
#pragma unroll
        for (int nt = 0; nt < 4; ++nt) {
            int oc = nt * 16 + n;
            int plx = mt * 8 + q * 2;
            pool[wsub][plx][oc]     = fmaxf(acc[mt][nt][0], acc[mt][nt][1]);
            pool[wsub][plx + 1][oc] = fmaxf(acc[mt][nt][2], acc[mt][nt][3]);
        }
    __syncthreads();

    {
        int plx = tid >> 2, ocq = tid & 3;
        int wp = plx >> 5, pl = plx & 31;
        __attribute__((aligned(16))) ushort hb[16], lb[16];
#pragma unroll
        for (int e = 0; e < 16; ++e) {
            int oc = ocq * 16 + e;
            float v = fmaxf(pool[wp * 2][pl][oc], pool[wp * 2 + 1][pl][oc]);
            v = fmaxf(v + bias[oc], 0.f);
            ushort h = f2bf(v);
            hb[e] = h;
            lb[e] = f2bf(v - bf2f(h));
        }
        int gx = seg * 64 + plx;
        int cpl = (stream_base >> 5) + (ocq >> 1);
        int cho = (ocq & 1) * 16;
        size_t base = (((size_t)(((b * 4 + cpl) * 128 + Y) * 128 + gx)) << 5) + cho;
        uint4* dh = (uint4*)(Ahi + base);
        uint4* dl = (uint4*)(Alo + base);
        dh[0] = *(const uint4*)&hb[0];
        dh[1] = *(const uint4*)&hb[8];
        dl[0] = *(const uint4*)&lb[0];
        dl[1] = *(const uint4*)&lb[8];
    }
}

// ---------- wprep: fuse_w fp32 -> fragment-ordered bf16 hi/lo + feat zero ---
// CHUNK-MAJOR: Wf[c][t][oc][kk] = W[oc][ic=c*32+kk][ky=t/3][kx=t%3]
__global__ __launch_bounds__(256) void wprep(
    const float* __restrict__ fw, ushort* __restrict__ Whi,
    ushort* __restrict__ Wlo, float* __restrict__ feat)
{
    int idx = blockIdx.x * 256 + threadIdx.x;
    if (blockIdx.x == 0) {
#pragma unroll
        for (int k = 0; k < 4; ++k) feat[threadIdx.x + k * 256] = 0.f;
    }
    if (idx >= 147456) return;
    int kk = idx & 31;
    int oc = (idx >> 5) & 127;
    int ct = idx >> 12;           // 0..35 = c*9 + t
    int c = ct / 9, t = ct - c * 9;
    int ic = c * 32 + kk;
    int ky = t / 3, kx = t - ky * 3;
    float v = fw[((oc * 128 + ic) * 3 + ky) * 3 + kx];
    ushort h = f2bf(v);
    Whi[idx] = h;
    Wlo[idx] = f2bf(v - bf2f(h));
}

// ---------- Kernel C: fuse conv via split-bf16 MFMA + relu + global mean ----
// R11 shape (256px x 128oc, wave = 64px x 128oc) + WAVE DE-PHASING: each
// wave's chunk order rotated by ((wsub+ypair)&3)*9 tc-steps so co-resident
// waves (same SIMD, different blocks / different wsub) stall out of phase.
__global__ __launch_bounds__(256, 2) void fuse_mfma(
    const ushort* __restrict__ Ahi, const ushort* __restrict__ Alo,
    const ushort* __restrict__ Whi, const ushort* __restrict__ Wlo,
    const float* __restrict__ bias, float* __restrict__ featsum)
{
    __shared__ float partial[4][128];
    const int b = blockIdx.x, ypair = blockIdx.y;
    const int tid = threadIdx.x, wsub = tid >> 6, lane = tid & 63;
    const int n = lane & 15, q = lane >> 4;
    const int y = ypair * 2 + (wsub >> 1);       // conv row for this wave
    const int xbase = (wsub & 1) * 64;           // wave covers x [xbase,xbase+64)
    const int rot = ((wsub + ypair) & 3) * 9;    // chunk rotation (de-phase)

    f32x4 acc[4][8];
#pragma unroll
    for (int mt = 0; mt < 4; ++mt)
#pragma unroll
        for (int g = 0; g < 8; ++g) acc[mt][g] = (f32x4){0.f, 0.f, 0.f, 0.f};

    const uint4 zero4 = make_uint4(0u, 0u, 0u, 0u);

    auto loadA = [&](int tc, uint4* oh, uint4* ol) {
        int c = tc / 9, t = tc - c * 9;   // chunk-major decode
        int ky = t / 3, kx = t - ky * 3;
        int yy = y + ky - 1;
        bool yok = (yy >= 0) & (yy < 128);
#pragma unroll
        for (int mt = 0; mt < 4; ++mt) {
            int xp = xbase + mt * 16 + n + kx - 1;
            bool ok = yok & (xp >= 0) & (xp < 128);
            int yyc = ok ? yy : 0, xpc = ok ? xp : 0;
            size_t aoff = (((size_t)(((b * 4 + c) * 128 + yyc) * 128 + xpc)) << 5) + q * 8;
            oh[mt] = ok ? *(const uint4*)(Ahi + aoff) : zero4;
            ol[mt] = ok ? *(const uint4*)(Alo + aoff) : zero4;
        }
    };

    const int boff = n * 32 + q * 8;   // lane-fixed B offset

    uint4 pAh[4], pAl[4];
    loadA(rot, pAh, pAl);

    for (int tc = 0; tc < 36; ++tc) {
        int s = tc + rot; if (s >= 36) s -= 36;       // rotated tc
        uint4 cAh[4], cAl[4];
#pragma unroll
        for (int mt = 0; mt < 4; ++mt) { cAh[mt] = pAh[mt]; cAl[mt] = pAl[mt]; }
        if (tc + 1 < 36) {
            int sn = tc + 1 + rot; if (sn >= 36) sn -= 36;
            loadA(sn, pAh, pAl);
        }
        const ushort* bhp = Whi + s * 4096 + boff;
        const ushort* blp = Wlo + s * 4096 + boff;
#pragma unroll
        for (int g = 0; g < 8; ++g) {
            bf16x8 bh = __builtin_bit_cast(bf16x8, *(const uint4*)(bhp + g * 512));
            bf16x8 bl = __builtin_bit_cast(bf16x8, *(const uint4*)(blp + g * 512));
#pragma unroll
            for (int mt = 0; mt < 4; ++mt) {
                bf16x8 ah = __builtin_bit_cast(bf16x8, cAh[mt]);
                acc[mt][g] = __builtin_amdgcn_mfma_f32_16x16x32_bf16(ah, bh, acc[mt][g], 0, 0, 0);
            }
#pragma unroll
            for (int mt = 0; mt < 4; ++mt) {
                bf16x8 ah = __builtin_bit_cast(bf16x8, cAh[mt]);
                acc[mt][g] = __builtin_amdgcn_mfma_f32_16x16x32_bf16(ah, bl, acc[mt][g], 0, 0, 0);
            }
#pragma unroll
            for (int mt = 0; mt < 4; ++mt) {
                bf16x8 al = __builtin_bit_cast(bf16x8, cAl[mt]);
                acc[mt][g] = __builtin_amdgcn_mfma_f32_16x16x32_bf16(al, bh, acc[mt][g], 0, 0, 0);
            }
        }
    }

    // Epilogue: lane (q,n) of tile (mt,g) holds D[px = q*4+r][oc = g*16+n].
#pragma unroll
    for (int g = 0; g < 8; ++g) {
        float bv = bias[g * 16 + n];
        float v = 0.f;
#pragma unroll
        for (int mt = 0; mt < 4; ++mt)
#pragma unroll
            for (int r = 0; r < 4; ++r) v += fmaxf(acc[mt][g][r] + bv, 0.f);
        v += __shfl_xor(v, 16);
        v += __shfl_xor(v, 32);
        if (lane < 16) partial[wsub][g * 16 + lane] = v;
    }
    __syncthreads();
    if (tid < 128) {
        float v = partial[0][tid] + partial[1][tid] + partial[2][tid] + partial[3][tid];
        atomicAdd(&featsum[b * 128 + tid], v);
    }
}

// ---------- Kernel D: det head + sigmoid + NMS + outputs --------------------
__global__ void det_nms(const float* __restrict__ featsum,
                        const float* __restrict__ dw, const float* __restrict__ db,
                        float* __restrict__ out)
{
    const int b = threadIdx.x;
    if (b >= 8) return;
    const float inv = 1.0f / 16384.0f;

    float p[18];
    for (int j = 0; j < 18; ++j) {
        float a = db[j];
        const float* wp = &dw[j * 128];
        const float* f = &featsum[b * 128];
        for (int c = 0; c < 128; ++c) a = fmaf(wp[c], f[c] * inv, a);
        p[j] = a;
    }
    for (int a = 0; a < 3; ++a)
        for (int e = 0; e < 6; ++e) out[b * 18 + a * 6 + e] = p[a * 6 + e];

    float bx[3][4], sc[3];
    bool ck[3];
    for (int a = 0; a < 3; ++a) {
        for (int k = 0; k < 4; ++k) {
            bx[a][k] = p[a * 6 + k];
            out[144 + b * 12 + a * 4 + k] = bx[a][k];
        }
        float sg = 1.f / (1.f + expf(-p[a * 6 + 4]));
        sc[a] = sg;
        ck[a] = sg > 0.5f;
        out[240 + b * 3 + a] = sg;
    }

    float key[3];
    int order[3];
    bool used[3] = {false, false, false};
    for (int a = 0; a < 3; ++a) key[a] = ck[a] ? sc[a] : -INFINITY;
    for (int i = 0; i < 3; ++i) {
        int best = -1;
        float bk = 0.f;
        for (int a = 0; a < 3; ++a) {
            if (used[a]) continue;
            if (best < 0 || key[a] > bk) { best = a; bk = key[a]; }
        }
        order[i] = best;
        used[best] = true;
    }

    float X1[3], Y1[3], X2[3], Y2[3], AR[3];
    for (int i = 0; i < 3; ++i) {
        int o = order[i];
        X1[i] = bx[o][0]; Y1[i] = bx[o][1];
        X2[i] = bx[o][2]; Y2[i] = bx[o][3];
        AR[i] = (X2[i] - X1[i]) * (Y2[i] - Y1[i]);
    }
    bool suppressed[3] = {false, false, false}, keep_s[3];
    for (int i = 0; i < 3; ++i) {
        bool valid = !suppressed[i];
        keep_s[i] = valid;
        if (valid) {
            for (int j = i + 1; j < 3; ++j) {
                float ix1 = fmaxf(X1[i], X1[j]), iy1 = fmaxf(Y1[i], Y1[j]);
                float ix2 = fminf(X2[i], X2[j]), iy2 = fminf(Y2[i], Y2[j]);
                float inter = fmaxf(ix2 - ix1, 0.f) * fmaxf(iy2 - iy1, 0.f);
                float iou = inter / (AR[i] + AR[j] - inter);
                if (iou > 0.5f) suppressed[j] = true;
            }
        }
    }
    bool keep[3];
    for (int i = 0; i < 3; ++i) keep[order[i]] = keep_s[i];
    for (int a = 0; a < 3; ++a)
        out[264 + b * 3 + a] = (keep[a] && ck[a]) ? 1.f : 0.f;
}

// ---------------------------------------------------------------------------
extern "C" void kernel_launch(void* const* d_in, const int* in_sizes, int n_in,
                              void* d_out, int out_size, void* d_ws, size_t ws_size,
                              hipStream_t stream)
{
    const float* x      = (const float*)d_in[0];
    const float* rgb_w1 = (const float*)d_in[1];
    const float* rgb_b1 = (const float*)d_in[2];
    const float* rgb_w2 = (const float*)d_in[3];
    const float* rgb_b2 = (const float*)d_in[4];
    const float* ir_w1  = (const float*)d_in[5];
    const float* ir_b1  = (const float*)d_in[6];
    const float* ir_w2  = (const float*)d_in[7];
    const float* ir_b2  = (const float*)d_in[8];
    const float* fuse_w = (const float*)d_in[9];
    const float* fuse_b = (const float*)d_in[10];
    const float* det_w  = (const float*)d_in[11];
    const float* det_b  = (const float*)d_in[12];
    float* out = (float*)d_out;

    char* ws = (char*)d_ws;
    ushort* C1h  = (ushort*)(ws);                         // 33,554,432 B
    ushort* C1l  = (ushort*)(ws + 33554432);              // 33,554,432 B
    // post-conv2 reuse of the C1 region:
    ushort* Whi  = (ushort*)(ws);                         // 299,008 B span
    ushort* Wlo  = (ushort*)(ws + 299008);                // 299,008 B span
    float*  feat = (float*)(ws + 598016);                 // 4,096 B
    ushort* Ahi  = (ushort*)(ws + 67108864);              // 33,554,432 B
    ushort* Alo  = (ushort*)(ws + 100663296);             // 33,554,432 B

    dim3 blk(256);
    hipLaunchKernelGGL(conv1_pool, dim3(16, 16, 8), blk, 0, stream, x, rgb_w1, rgb_b1, C1h, C1l);
    hipLaunchKernelGGL(conv2_mfma, dim3(2, 128, 8), blk, 0, stream, C1h, C1l, rgb_w2, rgb_b2, Ahi, Alo, 0);
    hipLaunchKernelGGL(conv1_pool, dim3(16, 16, 8), blk, 0, stream, x, ir_w1, ir_b1, C1h, C1l);
    hipLaunchKernelGGL(conv2_mfma, dim3(2, 128, 8), blk, 0, stream, C1h, C1l, ir_w2, ir_b2, Ahi, Alo, 64);
    hipLaunchKernelGGL(wprep, dim3(576), blk, 0, stream, fuse_w, Whi, Wlo, feat);
    hipLaunchKernelGGL(fuse_mfma, dim3(8, 64), blk, 0, stream, Ahi, Alo, Whi, Wlo, fuse_b, feat);
    hipLaunchKernelGGL(det_nms, dim3(1), dim3(64), 0, stream, feat, det_w, det_b, out);
}

// Round 15
// 591.916 us; speedup vs baseline: 1.0368x; 1.0368x over previous
//
#include <hip/hip_runtime.h>
#include <math.h>

// ---------------------------------------------------------------------------
// MultiStreamCNN. R15: revert R14 (both changes regressed: conv2 transpose
// stageB added 1.1e7 LDS conflicts + VALU 43%; fuse de-phasing neutral).
// Back to R13 baseline (544.5us) with ONE change: fuse's 36-step tc loop is
// FULLY UNROLLED (and the neutral rolling B prefetch dropped) — tc/9
// division, boundary masks and 64-bit address builds constant-fold; B
// offsets become immediates; compiler pipelines A-loads across iterations
// (no barriers in loop). Same accumulation order as R11/R13 (absmax 0.0).
// ---------------------------------------------------------------------------

typedef __bf16 bf16x8 __attribute__((ext_vector_type(8)));
typedef float f32x4 __attribute__((ext_vector_type(4)));

static __device__ __forceinline__ ushort f2bf(float f) {
    unsigned u = __float_as_uint(f);
    unsigned r = (u + 0x7fffu + ((u >> 16) & 1u)) >> 16;   // RNE
    return (ushort)r;
}
static __device__ __forceinline__ float bf2f(ushort h) {
    return __uint_as_float(((unsigned)h) << 16);
}

// ---------- Kernel A: conv3x3 (3->32) + bias + relu + maxpool2 --------------
__global__ __launch_bounds__(256) void conv1_pool(
    const float* __restrict__ x, const float* __restrict__ w,
    const float* __restrict__ bias, ushort* __restrict__ C1h,
    ushort* __restrict__ C1l)
{
    __shared__ float s[3 * 34 * 34];
    const int b = blockIdx.z;
    const int tileX = blockIdx.x, tileY = blockIdx.y;
    const int tid = threadIdx.x;
    const int tx = tid & 15, ty = tid >> 4;
    const int ih0 = tileY * 32 - 1, iw0 = tileX * 32 - 1;

    for (int i = tid; i < 3 * 34 * 34; i += 256) {
        int c = i / 1156, r = i % 1156;
        int y = r / 34, xx = r % 34;
        int ih = ih0 + y, iw = iw0 + xx;
        float v = 0.f;
        if (ih >= 0 && ih < 512 && iw >= 0 && iw < 512)
            v = x[((b * 3 + c) * 512 + ih) * 512 + iw];
        s[i] = v;
    }
    __syncthreads();

    float in[3][4][4];
#pragma unroll
    for (int c = 0; c < 3; ++c)
#pragma unroll
        for (int dy = 0; dy < 4; ++dy)
#pragma unroll
            for (int dx = 0; dx < 4; ++dx)
                in[c][dy][dx] = s[c * 1156 + (2 * ty + dy) * 34 + (2 * tx + dx)];

    const int oh = tileY * 16 + ty, ow = tileX * 16 + tx;
    __attribute__((aligned(16))) ushort hb[32];
    __attribute__((aligned(16))) ushort lb[32];
#pragma unroll
    for (int oc = 0; oc < 32; ++oc) {   // FULL unroll: hb/lb must stay in VGPRs
        const float bv = bias[oc];
        float m = -INFINITY;
#pragma unroll
        for (int py = 0; py < 2; ++py)
#pragma unroll
            for (int px = 0; px < 2; ++px) {
                float a = 0.f;
#pragma unroll
                for (int c = 0; c < 3; ++c)
#pragma unroll
                    for (int ky = 0; ky < 3; ++ky)
#pragma unroll
                        for (int kx = 0; kx < 3; ++kx)
                            a = fmaf(w[((oc * 3 + c) * 3 + ky) * 3 + kx],
                                     in[c][py + ky][px + kx], a);
                m = fmaxf(m, a);
            }
        m = fmaxf(m + bv, 0.f);
        ushort h = f2bf(m);
        hb[oc] = h;
        lb[oc] = f2bf(m - bf2f(h));
    }
    size_t base = ((size_t)((b * 256 + oh) * 256 + ow)) << 5;
    uint4* dh = (uint4*)(C1h + base);
    uint4* dl = (uint4*)(C1l + base);
#pragma unroll
    for (int k = 0; k < 4; ++k) {
        dh[k] = *(const uint4*)&hb[k * 8];
        dl[k] = *(const uint4*)&lb[k * 8];
    }
}

// ---------- Kernel B: conv2 as split-bf16 MFMA + maxpool2 -------------------
// Phased B staging (taps 0-4 then 5-8): LDS 40960 B -> 4 blocks/CU.
// Output CHUNK-PLANAR A[b][c(4)][y][x][32].  (R13 version, verified best.)
__global__ __launch_bounds__(256) void conv2_mfma(
    const ushort* __restrict__ C1h, const ushort* __restrict__ C1l,
    const float* __restrict__ w2, const float* __restrict__ bias,
    ushort* __restrict__ Ahi, ushort* __restrict__ Alo, int stream_base)
{
    __shared__ char lds[40960];            // union: B (40KB) then pool (32KB)
    ushort* Bh = (ushort*)lds;             // [rel_tap][oc*32+kk]
    ushort* Bl = (ushort*)(lds + 20480);
    float (*pool)[32][64] = (float (*)[32][64])lds;  // [4][32][64], after taps

    const int seg = blockIdx.x, Y = blockIdx.y, b = blockIdx.z;
    const int tid = threadIdx.x, wsub = tid >> 6, lane = tid & 63;
    const int n = lane & 15, q = lane >> 4;
    const int yc = 2 * Y + (wsub & 1);              // conv row in [0,256)
    const int wx0 = seg * 128 + (wsub >> 1) * 64;   // conv x base for wave

    const uint4 zero4 = make_uint4(0u, 0u, 0u, 0u);

    auto stageB = [&](int t0, int ntap) {
        for (int i = tid; i < ntap * 2048; i += 256) {
            int t = t0 + (i >> 11), r = i & 2047;
            float v = w2[r * 9 + t];
            ushort h = f2bf(v);
            Bh[i] = h;
            Bl[i] = f2bf(v - bf2f(h));
        }
    };

    auto loadA = [&](int t, uint4* aH, uint4* aL) {
        int ky = t / 3, kx = t - ky * 3;
        int yy = yc + ky - 1;
        bool yok = (yy >= 0) & (yy < 256);
#pragma unroll
        for (int mt = 0; mt < 4; ++mt) {
            int xp = wx0 + mt * 16 + n + kx - 1;
            bool ok = yok & (xp >= 0) & (xp < 256);
            int yyc = ok ? yy : 0, xpc = ok ? xp : 0;
            size_t off = (((size_t)((b * 256 + yyc) * 256 + xpc)) << 5) + q * 8;
            aH[mt] = ok ? *(const uint4*)(C1h + off) : zero4;
            aL[mt] = ok ? *(const uint4*)(C1l + off) : zero4;
        }
    };

    f32x4 acc[4][4];
#pragma unroll
    for (int mt = 0; mt < 4; ++mt)
#pragma unroll
        for (int nt = 0; nt < 4; ++nt) acc[mt][nt] = (f32x4){0.f, 0.f, 0.f, 0.f};

    uint4 aH[4], aL[4];
    loadA(0, aH, aL);
    stageB(0, 5);
    __syncthreads();   // phase-0 B staged

    for (int t = 0; t < 9; ++t) {
        if (t == 5) {               // phase switch: restage taps 5-8
            __syncthreads();        // all phase-0 B reads done
            stageB(5, 4);
            __syncthreads();
        }
        const int rel = (t < 5) ? t : t - 5;
        uint4 cH[4], cL[4];
#pragma unroll
        for (int mt = 0; mt < 4; ++mt) { cH[mt] = aH[mt]; cL[mt] = aL[mt]; }
        if (t + 1 < 9) loadA(t + 1, aH, aL);
        bf16x8 bh[4], bl[4];
#pragma unroll
        for (int nt = 0; nt < 4; ++nt) {
            int off = rel * 2048 + (nt * 16 + n) * 32 + q * 8;
            bh[nt] = __builtin_bit_cast(bf16x8, *(const uint4*)&Bh[off]);
            bl[nt] = __builtin_bit_cast(bf16x8, *(const uint4*)&Bl[off]);
        }
        // step-outer MFMA order (dep distance 16)
#pragma unroll
        for (int mt = 0; mt < 4; ++mt) {
            bf16x8 ah = __builtin_bit_cast(bf16x8, cH[mt]);
#pragma unroll
            for (int nt = 0; nt < 4; ++nt)
                acc[mt][nt] = __builtin_amdgcn_mfma_f32_16x16x32_bf16(ah, bh[nt], acc[mt][nt], 0, 0, 0);
        }
#pragma unroll
        for (int mt = 0; mt < 4; ++mt) {
            bf16x8 ah = __builtin_bit_cast(bf16x8, cH[mt]);
#pragma unroll
            for (int nt = 0; nt < 4; ++nt)
                acc[mt][nt] = __builtin_amdgcn_mfma_f32_16x16x32_bf16(ah, bl[nt], acc[mt][nt], 0, 0, 0);
        }
#pragma unroll
        for (int mt = 0; mt < 4; ++mt) {
            bf16x8 al = __builtin_bit_cast(bf16x8, cL[mt]);
#pragma unroll
            for (int nt = 0; nt < 4; ++nt)
                acc[mt][nt] = __builtin_amdgcn_mfma_f32_16x16x32_bf16(al, bh[nt], acc[mt][nt], 0, 0, 0);
        }
    }

    __syncthreads();   // all B reads done; safe to overwrite with pool

#pragma unroll
    for (int mt = 0; mt < 4; ++mt)
#pragma unroll
        for (int nt = 0; nt < 4; ++nt) {
            int oc = nt * 16 + n;
            int plx = mt * 8 + q * 2;
            pool[wsub][plx][oc]     = fmaxf(acc[mt][nt][0], acc[mt][nt][1]);
            pool[wsub][plx + 1][oc] = fmaxf(acc[mt][nt][2], acc[mt][nt][3]);
        }
    __syncthreads();

    {
        int plx = tid >> 2, ocq = tid & 3;
        int wp = plx >> 5, pl = plx & 31;
        __attribute__((aligned(16))) ushort hb[16], lb[16];
#pragma unroll
        for (int e = 0; e < 16; ++e) {
            int oc = ocq * 16 + e;
            float v = fmaxf(pool[wp * 2][pl][oc], pool[wp * 2 + 1][pl][oc]);
            v = fmaxf(v + bias[oc], 0.f);
            ushort h = f2bf(v);
            hb[e] = h;
            lb[e] = f2bf(v - bf2f(h));
        }
        int gx = seg * 64 + plx;
        int cpl = (stream_base >> 5) + (ocq >> 1);
        int cho = (ocq & 1) * 16;
        size_t base = (((size_t)(((b * 4 + cpl) * 128 + Y) * 128 + gx)) << 5) + cho;
        uint4* dh = (uint4*)(Ahi + base);
        uint4* dl = (uint4*)(Alo + base);
        dh[0] = *(const uint4*)&hb[0];
        dh[1] = *(const uint4*)&hb[8];
        dl[0] = *(const uint4*)&lb[0];
        dl[1] = *(const uint4*)&lb[8];
    }
}

// ---------- wprep: fuse_w fp32 -> fragment-ordered bf16 hi/lo + feat zero ---
// CHUNK-MAJOR: Wf[c][t][oc][kk] = W[oc][ic=c*32+kk][ky=t/3][kx=t%3]
__global__ __launch_bounds__(256) void wprep(
    const float* __restrict__ fw, ushort* __restrict__ Whi,
    ushort* __restrict__ Wlo, float* __restrict__ feat)
{
    int idx = blockIdx.x * 256 + threadIdx.x;
    if (blockIdx.x == 0) {
#pragma unroll
        for (int k = 0; k < 4; ++k) feat[threadIdx.x + k * 256] = 0.f;
    }
    if (idx >= 147456) return;
    int kk = idx & 31;
    int oc = (idx >> 5) & 127;
    int ct = idx >> 12;           // 0..35 = c*9 + t
    int c = ct / 9, t = ct - c * 9;
    int ic = c * 32 + kk;
    int ky = t / 3, kx = t - ky * 3;
    float v = fw[((oc * 128 + ic) * 3 + ky) * 3 + kx];
    ushort h = f2bf(v);
    Whi[idx] = h;
    Wlo[idx] = f2bf(v - bf2f(h));
}

// ---------- Kernel C: fuse conv via split-bf16 MFMA + relu + global mean ----
// R11 shape (256px x 128oc, wave = 64px x 128oc). tc loop FULLY UNROLLED:
// c/t/ky/kx constant-fold, masks hoisted, B offsets immediate. No barriers
// in the loop; compiler pipelines A-loads across iterations.
__global__ __launch_bounds__(256, 2) void fuse_mfma(
    const ushort* __restrict__ Ahi, const ushort* __restrict__ Alo,
    const ushort* __restrict__ Whi, const ushort* __restrict__ Wlo,
    const float* __restrict__ bias, float* __restrict__ featsum)
{
    __shared__ float partial[4][128];
    const int b = blockIdx.x, ypair = blockIdx.y;
    const int tid = threadIdx.x, wsub = tid >> 6, lane = tid & 63;
    const int n = lane & 15, q = lane >> 4;
    const int y = ypair * 2 + (wsub >> 1);       // conv row for this wave
    const int xbase = (wsub & 1) * 64;           // wave covers x [xbase,xbase+64)

    f32x4 acc[4][8];
#pragma unroll
    for (int mt = 0; mt < 4; ++mt)
#pragma unroll
        for (int g = 0; g < 8; ++g) acc[mt][g] = (f32x4){0.f, 0.f, 0.f, 0.f};

    const uint4 zero4 = make_uint4(0u, 0u, 0u, 0u);

    auto loadA = [&](int tc, uint4* oh, uint4* ol) {
        int c = tc / 9, t = tc - c * 9;   // constant-folds under full unroll
        int ky = t / 3, kx = t - ky * 3;
        int yy = y + ky - 1;
        bool yok = (yy >= 0) & (yy < 128);
#pragma unroll
        for (int mt = 0; mt < 4; ++mt) {
            int xp = xbase + mt * 16 + n + kx - 1;
            bool ok = yok & (xp >= 0) & (xp < 128);
            int yyc = ok ? yy : 0, xpc = ok ? xp : 0;
            size_t aoff = (((size_t)(((b * 4 + c) * 128 + yyc) * 128 + xpc)) << 5) + q * 8;
            oh[mt] = ok ? *(const uint4*)(Ahi + aoff) : zero4;
            ol[mt] = ok ? *(const uint4*)(Alo + aoff) : zero4;
        }
    };

    const int boff = n * 32 + q * 8;   // lane-fixed B offset

    uint4 pAh[4], pAl[4];
    loadA(0, pAh, pAl);

#pragma unroll
    for (int tc = 0; tc < 36; ++tc) {
        uint4 cAh[4], cAl[4];
#pragma unroll
        for (int mt = 0; mt < 4; ++mt) { cAh[mt] = pAh[mt]; cAl[mt] = pAl[mt]; }
        if (tc + 1 < 36) loadA(tc + 1, pAh, pAl);
        const ushort* bhp = Whi + tc * 4096 + boff;
        const ushort* blp = Wlo + tc * 4096 + boff;
#pragma unroll
        for (int g = 0; g < 8; ++g) {
            bf16x8 bh = __builtin_bit_cast(bf16x8, *(const uint4*)(bhp + g * 512));
            bf16x8 bl = __builtin_bit_cast(bf16x8, *(const uint4*)(blp + g * 512));
#pragma unroll
            for (int mt = 0; mt < 4; ++mt) {
                bf16x8 ah = __builtin_bit_cast(bf16x8, cAh[mt]);
                acc[mt][g] = __builtin_amdgcn_mfma_f32_16x16x32_bf16(ah, bh, acc[mt][g], 0, 0, 0);
            }
#pragma unroll
            for (int mt = 0; mt < 4; ++mt) {
                bf16x8 ah = __builtin_bit_cast(bf16x8, cAh[mt]);
                acc[mt][g] = __builtin_amdgcn_mfma_f32_16x16x32_bf16(ah, bl, acc[mt][g], 0, 0, 0);
            }
#pragma unroll
            for (int mt = 0; mt < 4; ++mt) {
                bf16x8 al = __builtin_bit_cast(bf16x8, cAl[mt]);
                acc[mt][g] = __builtin_amdgcn_mfma_f32_16x16x32_bf16(al, bh, acc[mt][g], 0, 0, 0);
            }
        }
    }

    // Epilogue: lane (q,n) of tile (mt,g) holds D[px = q*4+r][oc = g*16+n].
#pragma unroll
    for (int g = 0; g < 8; ++g) {
        float bv = bias[g * 16 + n];
        float v = 0.f;
#pragma unroll
        for (int mt = 0; mt < 4; ++mt)
#pragma unroll
            for (int r = 0; r < 4; ++r) v += fmaxf(acc[mt][g][r] + bv, 0.f);
        v += __shfl_xor(v, 16);
        v += __shfl_xor(v, 32);
        if (lane < 16) partial[wsub][g * 16 + lane] = v;
    }
    __syncthreads();
    if (tid < 128) {
        float v = partial[0][tid] + partial[1][tid] + partial[2][tid] + partial[3][tid];
        atomicAdd(&featsum[b * 128 + tid], v);
    }
}

// ---------- Kernel D: det head + sigmoid + NMS + outputs --------------------
__global__ void det_nms(const float* __restrict__ featsum,
                        const float* __restrict__ dw, const float* __restrict__ db,
                        float* __restrict__ out)
{
    const int b = threadIdx.x;
    if (b >= 8) return;
    const float inv = 1.0f / 16384.0f;

    float p[18];
    for (int j = 0; j < 18; ++j) {
        float a = db[j];
        const float* wp = &dw[j * 128];
        const float* f = &featsum[b * 128];
        for (int c = 0; c < 128; ++c) a = fmaf(wp[c], f[c] * inv, a);
        p[j] = a;
    }
    for (int a = 0; a < 3; ++a)
        for (int e = 0; e < 6; ++e) out[b * 18 + a * 6 + e] = p[a * 6 + e];

    float bx[3][4], sc[3];
    bool ck[3];
    for (int a = 0; a < 3; ++a) {
        for (int k = 0; k < 4; ++k) {
            bx[a][k] = p[a * 6 + k];
            out[144 + b * 12 + a * 4 + k] = bx[a][k];
        }
        float sg = 1.f / (1.f + expf(-p[a * 6 + 4]));
        sc[a] = sg;
        ck[a] = sg > 0.5f;
        out[240 + b * 3 + a] = sg;
    }

    float key[3];
    int order[3];
    bool used[3] = {false, false, false};
    for (int a = 0; a < 3; ++a) key[a] = ck[a] ? sc[a] : -INFINITY;
    for (int i = 0; i < 3; ++i) {
        int best = -1;
        float bk = 0.f;
        for (int a = 0; a < 3; ++a) {
            if (used[a]) continue;
            if (best < 0 || key[a] > bk) { best = a; bk = key[a]; }
        }
        order[i] = best;
        used[best] = true;
    }

    float X1[3], Y1[3], X2[3], Y2[3], AR[3];
    for (int i = 0; i < 3; ++i) {
        int o = order[i];
        X1[i] = bx[o][0]; Y1[i] = bx[o][1];
        X2[i] = bx[o][2]; Y2[i] = bx[o][3];
        AR[i] = (X2[i] - X1[i]) * (Y2[i] - Y1[i]);
    }
    bool suppressed[3] = {false, false, false}, keep_s[3];
    for (int i = 0; i < 3; ++i) {
        bool valid = !suppressed[i];
        keep_s[i] = valid;
        if (valid) {
            for (int j = i + 1; j < 3; ++j) {
                float ix1 = fmaxf(X1[i], X1[j]), iy1 = fmaxf(Y1[i], Y1[j]);
                float ix2 = fminf(X2[i], X2[j]), iy2 = fminf(Y2[i], Y2[j]);
                float inter = fmaxf(ix2 - ix1, 0.f) * fmaxf(iy2 - iy1, 0.f);
                float iou = inter / (AR[i] + AR[j] - inter);
                if (iou > 0.5f) suppressed[j] = true;
            }
        }
    }
    bool keep[3];
    for (int i = 0; i < 3; ++i) keep[order[i]] = keep_s[i];
    for (int a = 0; a < 3; ++a)
        out[264 + b * 3 + a] = (keep[a] && ck[a]) ? 1.f : 0.f;
}

// ---------------------------------------------------------------------------
extern "C" void kernel_launch(void* const* d_in, const int* in_sizes, int n_in,
                              void* d_out, int out_size, void* d_ws, size_t ws_size,
                              hipStream_t stream)
{
    const float* x      = (const float*)d_in[0];
    const float* rgb_w1 = (const float*)d_in[1];
    const float* rgb_b1 = (const float*)d_in[2];
    const float* rgb_w2 = (const float*)d_in[3];
    const float* rgb_b2 = (const float*)d_in[4];
    const float* ir_w1  = (const float*)d_in[5];
    const float* ir_b1  = (const float*)d_in[6];
    const float* ir_w2  = (const float*)d_in[7];
    const float* ir_b2  = (const float*)d_in[8];
    const float* fuse_w = (const float*)d_in[9];
    const float* fuse_b = (const float*)d_in[10];
    const float* det_w  = (const float*)d_in[11];
    const float* det_b  = (const float*)d_in[12];
    float* out = (float*)d_out;

    char* ws = (char*)d_ws;
    ushort* C1h  = (ushort*)(ws);                         // 33,554,432 B
    ushort* C1l  = (ushort*)(ws + 33554432);              // 33,554,432 B
    // post-conv2 reuse of the C1 region:
    ushort* Whi  = (ushort*)(ws);                         // 294,912 B
    ushort* Wlo  = (ushort*)(ws + 294912);                // 294,912 B
    float*  feat = (float*)(ws + 589824);                 // 4,096 B
    ushort* Ahi  = (ushort*)(ws + 67108864);              // 33,554,432 B
    ushort* Alo  = (ushort*)(ws + 100663296);             // 33,554,432 B

    dim3 blk(256);
    hipLaunchKernelGGL(conv1_pool, dim3(16, 16, 8), blk, 0, stream, x, rgb_w1, rgb_b1, C1h, C1l);
    hipLaunchKernelGGL(conv2_mfma, dim3(2, 128, 8), blk, 0, stream, C1h, C1l, rgb_w2, rgb_b2, Ahi, Alo, 0);
    hipLaunchKernelGGL(conv1_pool, dim3(16, 16, 8), blk, 0, stream, x, ir_w1, ir_b1, C1h, C1l);
    hipLaunchKernelGGL(conv2_mfma, dim3(2, 128, 8), blk, 0, stream, C1h, C1l, ir_w2, ir_b2, Ahi, Alo, 64);
    hipLaunchKernelGGL(wprep, dim3(576), blk, 0, stream, fuse_w, Whi, Wlo, feat);
    hipLaunchKernelGGL(fuse_mfma, dim3(8, 64), blk, 0, stream, Ahi, Alo, Whi, Wlo, fuse_b, feat);
    hipLaunchKernelGGL(det_nms, dim3(1), dim3(64), 0, stream, feat, det_w, det_b, out);
}

// Round 16
// 557.227 us; speedup vs baseline: 1.1014x; 1.0623x over previous
//
#include <hip/hip_runtime.h>
#include <math.h>

// ---------------------------------------------------------------------------
// MultiStreamCNN. R16: fuse switched to 32x32x16 MFMA (half the MFMA
// instructions at the better-measured rate, half the A-loads), everything
// else reverted to the R13 best (544.5us). R12-R15 showed fuse's ~40%
// MfmaUtil plateau is not schedulable away at fixed instruction mix.
//  A-frag:  m=lane&31, k=(lane>>5)*8+j  (1KB contiguous wave-load)
//  B-frag:  n=lane&31, k=(lane>>5)*8+j  (from existing W[s][oc][kk] layout)
//  C/D:     col(oc)=lane&31, row(px)=(reg&3)+8*(reg>>2)+4*(lane>>5)
// ---------------------------------------------------------------------------

typedef __bf16 bf16x8 __attribute__((ext_vector_type(8)));
typedef float f32x4 __attribute__((ext_vector_type(4)));
typedef float f32x16 __attribute__((ext_vector_type(16)));

static __device__ __forceinline__ ushort f2bf(float f) {
    unsigned u = __float_as_uint(f);
    unsigned r = (u + 0x7fffu + ((u >> 16) & 1u)) >> 16;   // RNE
    return (ushort)r;
}
static __device__ __forceinline__ float bf2f(ushort h) {
    return __uint_as_float(((unsigned)h) << 16);
}

// ---------- Kernel A: conv3x3 (3->32) + bias + relu + maxpool2 --------------
__global__ __launch_bounds__(256) void conv1_pool(
    const float* __restrict__ x, const float* __restrict__ w,
    const float* __restrict__ bias, ushort* __restrict__ C1h,
    ushort* __restrict__ C1l)
{
    __shared__ float s[3 * 34 * 34];
    const int b = blockIdx.z;
    const int tileX = blockIdx.x, tileY = blockIdx.y;
    const int tid = threadIdx.x;
    const int tx = tid & 15, ty = tid >> 4;
    const int ih0 = tileY * 32 - 1, iw0 = tileX * 32 - 1;

    for (int i = tid; i < 3 * 34 * 34; i += 256) {
        int c = i / 1156, r = i % 1156;
        int y = r / 34, xx = r % 34;
        int ih = ih0 + y, iw = iw0 + xx;
        float v = 0.f;
        if (ih >= 0 && ih < 512 && iw >= 0 && iw < 512)
            v = x[((b * 3 + c) * 512 + ih) * 512 + iw];
        s[i] = v;
    }
    __syncthreads();

    float in[3][4][4];
#pragma unroll
    for (int c = 0; c < 3; ++c)
#pragma unroll
        for (int dy = 0; dy < 4; ++dy)
#pragma unroll
            for (int dx = 0; dx < 4; ++dx)
                in[c][dy][dx] = s[c * 1156 + (2 * ty + dy) * 34 + (2 * tx + dx)];

    const int oh = tileY * 16 + ty, ow = tileX * 16 + tx;
    __attribute__((aligned(16))) ushort hb[32];
    __attribute__((aligned(16))) ushort lb[32];
#pragma unroll
    for (int oc = 0; oc < 32; ++oc) {   // FULL unroll: hb/lb must stay in VGPRs
        const float bv = bias[oc];
        float m = -INFINITY;
#pragma unroll
        for (int py = 0; py < 2; ++py)
#pragma unroll
            for (int px = 0; px < 2; ++px) {
                float a = 0.f;
#pragma unroll
                for (int c = 0; c < 3; ++c)
#pragma unroll
                    for (int ky = 0; ky < 3; ++ky)
#pragma unroll
                        for (int kx = 0; kx < 3; ++kx)
                            a = fmaf(w[((oc * 3 + c) * 3 + ky) * 3 + kx],
                                     in[c][py + ky][px + kx], a);
                m = fmaxf(m, a);
            }
        m = fmaxf(m + bv, 0.f);
        ushort h = f2bf(m);
        hb[oc] = h;
        lb[oc] = f2bf(m - bf2f(h));
    }
    size_t base = ((size_t)((b * 256 + oh) * 256 + ow)) << 5;
    uint4* dh = (uint4*)(C1h + base);
    uint4* dl = (uint4*)(C1l + base);
#pragma unroll
    for (int k = 0; k < 4; ++k) {
        dh[k] = *(const uint4*)&hb[k * 8];
        dl[k] = *(const uint4*)&lb[k * 8];
    }
}

// ---------- Kernel B: conv2 as split-bf16 MFMA + maxpool2 -------------------
// Phased B staging (taps 0-4 then 5-8): LDS 40960 B -> 4 blocks/CU.
// Output CHUNK-PLANAR A[b][c(4)][y][x][32].  (R13 version, verified best.)
__global__ __launch_bounds__(256) void conv2_mfma(
    const ushort* __restrict__ C1h, const ushort* __restrict__ C1l,
    const float* __restrict__ w2, const float* __restrict__ bias,
    ushort* __restrict__ Ahi, ushort* __restrict__ Alo, int stream_base)
{
    __shared__ char lds[40960];            // union: B (40KB) then pool (32KB)
    ushort* Bh = (ushort*)lds;             // [rel_tap][oc*32+kk]
    ushort* Bl = (ushort*)(lds + 20480);
    float (*pool)[32][64] = (float (*)[32][64])lds;  // [4][32][64], after taps

    const int seg = blockIdx.x, Y = blockIdx.y, b = blockIdx.z;
    const int tid = threadIdx.x, wsub = tid >> 6, lane = tid & 63;
    const int n = lane & 15, q = lane >> 4;
    const int yc = 2 * Y + (wsub & 1);              // conv row in [0,256)
    const int wx0 = seg * 128 + (wsub >> 1) * 64;   // conv x base for wave

    const uint4 zero4 = make_uint4(0u, 0u, 0u, 0u);

    auto stageB = [&](int t0, int ntap) {
        for (int i = tid; i < ntap * 2048; i += 256) {
            int t = t0 + (i >> 11), r = i & 2047;
            float v = w2[r * 9 + t];
            ushort h = f2bf(v);
            Bh[i] = h;
            Bl[i] = f2bf(v - bf2f(h));
        }
    };

    auto loadA = [&](int t, uint4* aH, uint4* aL) {
        int ky = t / 3, kx = t - ky * 3;
        int yy = yc + ky - 1;
        bool yok = (yy >= 0) & (yy < 256);
#pragma unroll
        for (int mt = 0; mt < 4; ++mt) {
            int xp = wx0 + mt * 16 + n + kx - 1;
            bool ok = yok & (xp >= 0) & (xp < 256);
            int yyc = ok ? yy : 0, xpc = ok ? xp : 0;
            size_t off = (((size_t)((b * 256 + yyc) * 256 + xpc)) << 5) + q * 8;
            aH[mt] = ok ? *(const uint4*)(C1h + off) : zero4;
            aL[mt] = ok ? *(const uint4*)(C1l + off) : zero4;
        }
    };

    f32x4 acc[4][4];
#pragma unroll
    for (int mt = 0; mt < 4; ++mt)
#pragma unroll
        for (int nt = 0; nt < 4; ++nt) acc[mt][nt] = (f32x4){0.f, 0.f, 0.f, 0.f};

    uint4 aH[4], aL[4];
    loadA(0, aH, aL);
    stageB(0, 5);
    __syncthreads();   // phase-0 B staged

    for (int t = 0; t < 9; ++t) {
        if (t == 5) {               // phase switch: restage taps 5-8
            __syncthreads();        // all phase-0 B reads done
            stageB(5, 4);
            __syncthreads();
        }
        const int rel = (t < 5) ? t : t - 5;
        uint4 cH[4], cL[4];
#pragma unroll
        for (int mt = 0; mt < 4; ++mt) { cH[mt] = aH[mt]; cL[mt] = aL[mt]; }
        if (t + 1 < 9) loadA(t + 1, aH, aL);
        bf16x8 bh[4], bl[4];
#pragma unroll
        for (int nt = 0; nt < 4; ++nt) {
            int off = rel * 2048 + (nt * 16 + n) * 32 + q * 8;
            bh[nt] = __builtin_bit_cast(bf16x8, *(const uint4*)&Bh[off]);
            bl[nt] = __builtin_bit_cast(bf16x8, *(const uint4*)&Bl[off]);
        }
        // step-outer MFMA order (dep distance 16)
#pragma unroll
        for (int mt = 0; mt < 4; ++mt) {
            bf16x8 ah = __builtin_bit_cast(bf16x8, cH[mt]);
#pragma unroll
            for (int nt = 0; nt < 4; ++nt)
                acc[mt][nt] = __builtin_amdgcn_mfma_f32_16x16x32_bf16(ah, bh[nt], acc[mt][nt], 0, 0, 0);
        }
#pragma unroll
        for (int mt = 0; mt < 4; ++mt) {
            bf16x8 ah = __builtin_bit_cast(bf16x8, cH[mt]);
#pragma unroll
            for (int nt = 0; nt < 4; ++nt)
                acc[mt][nt] = __builtin_amdgcn_mfma_f32_16x16x32_bf16(ah, bl[nt], acc[mt][nt], 0, 0, 0);
        }
#pragma unroll
        for (int mt = 0; mt < 4; ++mt) {
            bf16x8 al = __builtin_bit_cast(bf16x8, cL[mt]);
#pragma unroll
            for (int nt = 0; nt < 4; ++nt)
                acc[mt][nt] = __builtin_amdgcn_mfma_f32_16x16x32_bf16(al, bh[nt], acc[mt][nt], 0, 0, 0);
        }
    }

    __syncthreads();   // all B reads done; safe to overwrite with pool

#pragma unroll
    for (int mt = 0; mt < 4; ++mt)
#pragma unroll
        for (int nt = 0; nt < 4; ++nt) {
            int oc = nt * 16 + n;
            int plx = mt * 8 + q * 2;
            pool[wsub][plx][oc]     = fmaxf(acc[mt][nt][0], acc[mt][nt][1]);
            pool[wsub][plx + 1][oc] = fmaxf(acc[mt][nt][2], acc[mt][nt][3]);
        }
    __syncthreads();

    {
        int plx = tid >> 2, ocq = tid & 3;
        int wp = plx >> 5, pl = plx & 31;
        __attribute__((aligned(16))) ushort hb[16], lb[16];
#pragma unroll
        for (int e = 0; e < 16; ++e) {
            int oc = ocq * 16 + e;
            float v = fmaxf(pool[wp * 2][pl][oc], pool[wp * 2 + 1][pl][oc]);
            v = fmaxf(v + bias[oc], 0.f);
            ushort h = f2bf(v);
            hb[e] = h;
            lb[e] = f2bf(v - bf2f(h));
        }
        int gx = seg * 64 + plx;
        int cpl = (stream_base >> 5) + (ocq >> 1);
        int cho = (ocq & 1) * 16;
        size_t base = (((size_t)(((b * 4 + cpl) * 128 + Y) * 128 + gx)) << 5) + cho;
        uint4* dh = (uint4*)(Ahi + base);
        uint4* dl = (uint4*)(Alo + base);
        dh[0] = *(const uint4*)&hb[0];
        dh[1] = *(const uint4*)&hb[8];
        dl[0] = *(const uint4*)&lb[0];
        dl[1] = *(const uint4*)&lb[8];
    }
}

// ---------- wprep: fuse_w fp32 -> fragment-ordered bf16 hi/lo + feat zero ---
// CHUNK-MAJOR: Wf[c][t][oc][kk] = W[oc][ic=c*32+kk][ky=t/3][kx=t%3]
__global__ __launch_bounds__(256) void wprep(
    const float* __restrict__ fw, ushort* __restrict__ Whi,
    ushort* __restrict__ Wlo, float* __restrict__ feat)
{
    int idx = blockIdx.x * 256 + threadIdx.x;
    if (blockIdx.x == 0) {
#pragma unroll
        for (int k = 0; k < 4; ++k) feat[threadIdx.x + k * 256] = 0.f;
    }
    if (idx >= 147456) return;
    int kk = idx & 31;
    int oc = (idx >> 5) & 127;
    int ct = idx >> 12;           // 0..35 = c*9 + t
    int c = ct / 9, t = ct - c * 9;
    int ic = c * 32 + kk;
    int ky = t / 3, kx = t - ky * 3;
    float v = fw[((oc * 128 + ic) * 3 + ky) * 3 + kx];
    ushort h = f2bf(v);
    Whi[idx] = h;
    Wlo[idx] = f2bf(v - bf2f(h));
}

// ---------- Kernel C: fuse conv via split-bf16 32x32x16 MFMA + mean ---------
// Block: 256 px (2 rows of 128) x 128 oc; wave = 64 px (2 M-tiles of 32) x
// 128 oc (4 N-tiles of 32). Per tc (chunk,tap): 2 K=16 slices x 3 split
// steps x 8 tiles = 48 MFMAs (was 96 of 16x16x32), 8 A-loads (was 16).
__global__ __launch_bounds__(256, 2) void fuse_mfma(
    const ushort* __restrict__ Ahi, const ushort* __restrict__ Alo,
    const ushort* __restrict__ Whi, const ushort* __restrict__ Wlo,
    const float* __restrict__ bias, float* __restrict__ featsum)
{
    __shared__ float partial[4][128];
    const int b = blockIdx.x, ypair = blockIdx.y;
    const int tid = threadIdx.x, wsub = tid >> 6, lane = tid & 63;
    const int l31 = lane & 31, lh = lane >> 5;   // lh in {0,1}
    const int y = ypair * 2 + (wsub >> 1);       // conv row for this wave
    const int xbase = (wsub & 1) * 64;           // wave covers x [xbase,xbase+64)

    f32x16 acc[2][4];
#pragma unroll
    for (int mt = 0; mt < 2; ++mt)
#pragma unroll
        for (int nt = 0; nt < 4; ++nt)
#pragma unroll
            for (int r = 0; r < 16; ++r) acc[mt][nt][r] = 0.f;

    const uint4 zero4 = make_uint4(0u, 0u, 0u, 0u);

    // A-frags: index [mt*2 + slice]; lane reads A[px=mt*32+l31][kk=slice*16+lh*8]
    auto loadA = [&](int tc, uint4* oh, uint4* ol) {
        int c = tc / 9, t = tc - c * 9;   // chunk-major decode
        int ky = t / 3, kx = t - ky * 3;
        int yy = y + ky - 1;
        bool yok = (yy >= 0) & (yy < 128);
#pragma unroll
        for (int mt = 0; mt < 2; ++mt) {
            int xp = xbase + mt * 32 + l31 + kx - 1;
            bool ok = yok & (xp >= 0) & (xp < 128);
            int yyc = ok ? yy : 0, xpc = ok ? xp : 0;
            size_t rowb = (((size_t)(((b * 4 + c) * 128 + yyc) * 128 + xpc)) << 5) + lh * 8;
#pragma unroll
            for (int s = 0; s < 2; ++s) {
                oh[mt * 2 + s] = ok ? *(const uint4*)(Ahi + rowb + s * 16) : zero4;
                ol[mt * 2 + s] = ok ? *(const uint4*)(Alo + rowb + s * 16) : zero4;
            }
        }
    };

    // lane-fixed B offset: oc = nt*32 + l31 -> +nt*1024; kk = slice*16 + lh*8
    const int boff = l31 * 32 + lh * 8;

    uint4 pAh[4], pAl[4];
    loadA(0, pAh, pAl);

    for (int tc = 0; tc < 36; ++tc) {
        uint4 cAh[4], cAl[4];
#pragma unroll
        for (int j = 0; j < 4; ++j) { cAh[j] = pAh[j]; cAl[j] = pAl[j]; }
        if (tc + 1 < 36) loadA(tc + 1, pAh, pAl);
        const ushort* bhp = Whi + tc * 4096 + boff;
        const ushort* blp = Wlo + tc * 4096 + boff;
#pragma unroll
        for (int s = 0; s < 2; ++s) {
            bf16x8 bh[4], bl[4];
#pragma unroll
            for (int nt = 0; nt < 4; ++nt) {
                bh[nt] = __builtin_bit_cast(bf16x8, *(const uint4*)(bhp + nt * 1024 + s * 16));
                bl[nt] = __builtin_bit_cast(bf16x8, *(const uint4*)(blp + nt * 1024 + s * 16));
            }
            // step-outer over the 8 accs (dep distance 8)
#pragma unroll
            for (int mt = 0; mt < 2; ++mt) {
                bf16x8 ah = __builtin_bit_cast(bf16x8, cAh[mt * 2 + s]);
#pragma unroll
                for (int nt = 0; nt < 4; ++nt)
                    acc[mt][nt] = __builtin_amdgcn_mfma_f32_32x32x16_bf16(ah, bh[nt], acc[mt][nt], 0, 0, 0);
            }
#pragma unroll
            for (int mt = 0; mt < 2; ++mt) {
                bf16x8 ah = __builtin_bit_cast(bf16x8, cAh[mt * 2 + s]);
#pragma unroll
                for (int nt = 0; nt < 4; ++nt)
                    acc[mt][nt] = __builtin_amdgcn_mfma_f32_32x32x16_bf16(ah, bl[nt], acc[mt][nt], 0, 0, 0);
            }
#pragma unroll
            for (int mt = 0; mt < 2; ++mt) {
                bf16x8 al = __builtin_bit_cast(bf16x8, cAl[mt * 2 + s]);
#pragma unroll
                for (int nt = 0; nt < 4; ++nt)
                    acc[mt][nt] = __builtin_amdgcn_mfma_f32_32x32x16_bf16(al, bh[nt], acc[mt][nt], 0, 0, 0);
            }
        }
    }

    // Epilogue: D col = oc_local = l31, rows = px within tile. Sum over px of
    // relu(acc + bias); lane^32 holds the complementary rows of the same oc.
#pragma unroll
    for (int nt = 0; nt < 4; ++nt) {
        float bv = bias[nt * 32 + l31];
        float v = 0.f;
#pragma unroll
        for (int mt = 0; mt < 2; ++mt)
#pragma unroll
            for (int r = 0; r < 16; ++r)
                v += fmaxf(acc[mt][nt][r] + bv, 0.f);
        v += __shfl_xor(v, 32);
        if (lane < 32) partial[wsub][nt * 32 + lane] = v;
    }
    __syncthreads();
    if (tid < 128) {
        float v = partial[0][tid] + partial[1][tid] + partial[2][tid] + partial[3][tid];
        atomicAdd(&featsum[b * 128 + tid], v);
    }
}

// ---------- Kernel D: det head + sigmoid + NMS + outputs --------------------
__global__ void det_nms(const float* __restrict__ featsum,
                        const float* __restrict__ dw, const float* __restrict__ db,
                        float* __restrict__ out)
{
    const int b = threadIdx.x;
    if (b >= 8) return;
    const float inv = 1.0f / 16384.0f;

    float p[18];
    for (int j = 0; j < 18; ++j) {
        float a = db[j];
        const float* wp = &dw[j * 128];
        const float* f = &featsum[b * 128];
        for (int c = 0; c < 128; ++c) a = fmaf(wp[c], f[c] * inv, a);
        p[j] = a;
    }
    for (int a = 0; a < 3; ++a)
        for (int e = 0; e < 6; ++e) out[b * 18 + a * 6 + e] = p[a * 6 + e];

    float bx[3][4], sc[3];
    bool ck[3];
    for (int a = 0; a < 3; ++a) {
        for (int k = 0; k < 4; ++k) {
            bx[a][k] = p[a * 6 + k];
            out[144 + b * 12 + a * 4 + k] = bx[a][k];
        }
        float sg = 1.f / (1.f + expf(-p[a * 6 + 4]));
        sc[a] = sg;
        ck[a] = sg > 0.5f;
        out[240 + b * 3 + a] = sg;
    }

    float key[3];
    int order[3];
    bool used[3] = {false, false, false};
    for (int a = 0; a < 3; ++a) key[a] = ck[a] ? sc[a] : -INFINITY;
    for (int i = 0; i < 3; ++i) {
        int best = -1;
        float bk = 0.f;
        for (int a = 0; a < 3; ++a) {
            if (used[a]) continue;
            if (best < 0 || key[a] > bk) { best = a; bk = key[a]; }
        }
        order[i] = best;
        used[best] = true;
    }

    float X1[3], Y1[3], X2[3], Y2[3], AR[3];
    for (int i = 0; i < 3; ++i) {
        int o = order[i];
        X1[i] = bx[o][0]; Y1[i] = bx[o][1];
        X2[i] = bx[o][2]; Y2[i] = bx[o][3];
        AR[i] = (X2[i] - X1[i]) * (Y2[i] - Y1[i]);
    }
    bool suppressed[3] = {false, false, false}, keep_s[3];
    for (int i = 0; i < 3; ++i) {
        bool valid = !suppressed[i];
        keep_s[i] = valid;
        if (valid) {
            for (int j = i + 1; j < 3; ++j) {
                float ix1 = fmaxf(X1[i], X1[j]), iy1 = fmaxf(Y1[i], Y1[j]);
                float ix2 = fminf(X2[i], X2[j]), iy2 = fminf(Y2[i], Y2[j]);
                float inter = fmaxf(ix2 - ix1, 0.f) * fmaxf(iy2 - iy1, 0.f);
                float iou = inter / (AR[i] + AR[j] - inter);
                if (iou > 0.5f) suppressed[j] = true;
            }
        }
    }
    bool keep[3];
    for (int i = 0; i < 3; ++i) keep[order[i]] = keep_s[i];
    for (int a = 0; a < 3; ++a)
        out[264 + b * 3 + a] = (keep[a] && ck[a]) ? 1.f : 0.f;
}

// ---------------------------------------------------------------------------
extern "C" void kernel_launch(void* const* d_in, const int* in_sizes, int n_in,
                              void* d_out, int out_size, void* d_ws, size_t ws_size,
                              hipStream_t stream)
{
    const float* x      = (const float*)d_in[0];
    const float* rgb_w1 = (const float*)d_in[1];
    const float* rgb_b1 = (const float*)d_in[2];
    const float* rgb_w2 = (const float*)d_in[3];
    const float* rgb_b2 = (const float*)d_in[4];
    const float* ir_w1  = (const float*)d_in[5];
    const float* ir_b1  = (const float*)d_in[6];
    const float* ir_w2  = (const float*)d_in[7];
    const float* ir_b2  = (const float*)d_in[8];
    const float* fuse_w = (const float*)d_in[9];
    const float* fuse_b = (const float*)d_in[10];
    const float* det_w  = (const float*)d_in[11];
    const float* det_b  = (const float*)d_in[12];
    float* out = (float*)d_out;

    char* ws = (char*)d_ws;
    ushort* C1h  = (ushort*)(ws);                         // 33,554,432 B
    ushort* C1l  = (ushort*)(ws + 33554432);              // 33,554,432 B
    // post-conv2 reuse of the C1 region:
    ushort* Whi  = (ushort*)(ws);                         // 294,912 B
    ushort* Wlo  = (ushort*)(ws + 294912);                // 294,912 B
    float*  feat = (float*)(ws + 589824);                 // 4,096 B
    ushort* Ahi  = (ushort*)(ws + 67108864);              // 33,554,432 B
    ushort* Alo  = (ushort*)(ws + 100663296);             // 33,554,432 B

    dim3 blk(256);
    hipLaunchKernelGGL(conv1_pool, dim3(16, 16, 8), blk, 0, stream, x, rgb_w1, rgb_b1, C1h, C1l);
    hipLaunchKernelGGL(conv2_mfma, dim3(2, 128, 8), blk, 0, stream, C1h, C1l, rgb_w2, rgb_b2, Ahi, Alo, 0);
    hipLaunchKernelGGL(conv1_pool, dim3(16, 16, 8), blk, 0, stream, x, ir_w1, ir_b1, C1h, C1l);
    hipLaunchKernelGGL(conv2_mfma, dim3(2, 128, 8), blk, 0, stream, C1h, C1l, ir_w2, ir_b2, Ahi, Alo, 64);
    hipLaunchKernelGGL(wprep, dim3(576), blk, 0, stream, fuse_w, Whi, Wlo, feat);
    hipLaunchKernelGGL(fuse_mfma, dim3(8, 64), blk, 0, stream, Ahi, Alo, Whi, Wlo, fuse_b, feat);
    hipLaunchKernelGGL(det_nms, dim3(1), dim3(64), 0, stream, feat, det_w, det_b, out);
}